// Round 13
// baseline (435.764 us; speedup 1.0000x reference)
//
#include <hip/hip_runtime.h>
#include <hip/hip_bf16.h>

#define HSTEP 0.1f
#define LN_EPS 1e-5f

typedef short short8 __attribute__((ext_vector_type(8)));
typedef float f32x4 __attribute__((ext_vector_type(4)));

__device__ __forceinline__ unsigned short f2bf(float f) {
  unsigned u = __builtin_bit_cast(unsigned, f);
  u += 0x7FFFu + ((u >> 16) & 1u);
  return (unsigned short)(u >> 16);
}
__device__ __forceinline__ float bf2f(unsigned short s) {
  unsigned u = ((unsigned)s) << 16;
  return __builtin_bit_cast(float, u);
}
__device__ __forceinline__ float bf2f_s(short s) { return bf2f((unsigned short)s); }

__device__ __forceinline__ unsigned cvt2(float a, float b) {
  unsigned r;
  asm("v_cvt_pk_bf16_f32 %0, %1, %2" : "=v"(r) : "v"(a), "v"(b));
  return r;
}
__device__ __forceinline__ short8 pk8(const float* v) {
  union { unsigned u[4]; short8 s; } w;
#pragma unroll
  for (int i = 0; i < 4; ++i) w.u[i] = cvt2(v[2 * i], v[2 * i + 1]);
  return w.s;
}

// intra-wave LDS fence: all prior DS ops done; no s_barrier (waves independent)
__device__ __forceinline__ void wait_lds() {
  __builtin_amdgcn_sched_barrier(0);
  asm volatile("s_waitcnt lgkmcnt(0)" ::: "memory");
  __builtin_amdgcn_sched_barrier(0);
}

// LDS-only block barrier (keeps global prefetch in flight)
__device__ __forceinline__ void bar_lds() {
  __builtin_amdgcn_sched_barrier(0);
  asm volatile("s_waitcnt lgkmcnt(0)" ::: "memory");
  __builtin_amdgcn_s_barrier();
  __builtin_amdgcn_sched_barrier(0);
}

__device__ __forceinline__ void stats_reduce(float ssum, float ssq, double* sOut) {
  for (int off = 32; off; off >>= 1) {
    ssum += __shfl_down(ssum, off);
    ssq  += __shfl_down(ssq, off);
  }
  __shared__ float rs_[4], rq_[4];
  int t = threadIdx.x;
  if ((t & 63) == 0) { rs_[t >> 6] = ssum; rq_[t >> 6] = ssq; }
  __syncthreads();
  if (t == 0) {
    atomicAdd(sOut + 0, (double)(rs_[0] + rs_[1] + rs_[2] + rs_[3]));
    atomicAdd(sOut + 1, (double)(rq_[0] + rq_[1] + rq_[2] + rq_[3]));
  }
}

__device__ __forceinline__ void ln_params(const double* sIn, long long cnt, float& mu, float& rs) {
  float cf = (float)cnt;
  float m = (float)sIn[0] / cf;
  float q = (float)sIn[1] / cf;
  mu = m;
  rs = rsqrtf(fmaxf(q - m * m, 0.f) + LN_EPS);
}

__device__ __forceinline__ void mfma192(const unsigned short (*feat)[200], const short8* bfr,
                                        int lane, int g, f32x4* acc) {
#pragma unroll
  for (int it = 0; it < 4; ++it)
#pragma unroll
    for (int k = 0; k < 6; ++k) {
      short8 a = *(const short8*)(&feat[it * 16 + (lane & 15)][k * 32 + g * 8]);
      acc[it] = __builtin_amdgcn_mfma_f32_16x16x32_bf16(a, bfr[k], acc[it], 0, 0, 0);
    }
}
__device__ __forceinline__ void mfma64t(const unsigned short (*at)[72], short8 b0, short8 b1,
                                        int lane, int g, f32x4* acc) {
#pragma unroll
  for (int it = 0; it < 4; ++it) {
    short8 a0 = *(const short8*)(&at[it * 16 + (lane & 15)][g * 8]);
    short8 a1 = *(const short8*)(&at[it * 16 + (lane & 15)][32 + g * 8]);
    acc[it] = __builtin_amdgcn_mfma_f32_16x16x32_bf16(a0, b0, acc[it], 0, 0, 0);
    acc[it] = __builtin_amdgcn_mfma_f32_16x16x32_bf16(a1, b1, acc[it], 0, 0, 0);
  }
}

// ---- all weights fp32 -> bf16 ----
__global__ __launch_bounds__(256) void k_cvt_all(
    const float* __restrict__ K1N, const float* __restrict__ K2N,
    const float* __restrict__ K1E, const float* __restrict__ K2E,
    const float* __restrict__ KNc, const float* __restrict__ KE1,
    const float* __restrict__ KE2, const float* __restrict__ KN1,
    const float* __restrict__ KN2, unsigned short* __restrict__ kw) {
  int i = blockIdx.x * 256 + threadIdx.x;
  if (i >= 86016) return;
  const float* s; int off;
  if (i < 4096)       { s = K1N; off = 0; }
  else if (i < 8192)  { s = K2N; off = 4096; }
  else if (i < 12288) { s = K1E; off = 8192; }
  else if (i < 16384) { s = K2E; off = 12288; }
  else if (i < 20480) { s = KNc; off = 16384; }
  else if (i < 45056) { s = KE1; off = 20480; }
  else if (i < 53248) { s = KE2; off = 45056; }
  else if (i < 77824) { s = KN1; off = 53248; }
  else                { s = KN2; off = 77824; }
  kw[i] = f2bf(s[i - off]);
}

// ==== CSR build ====
__global__ __launch_bounds__(256) void k_hist(const int* __restrict__ iInd,
                                              const int* __restrict__ jInd,
                                              int* __restrict__ cnt, long long E, int N) {
  long long e = (long long)blockIdx.x * 256 + threadIdx.x;
  if (e < E) {
    atomicAdd(cnt + iInd[e], 1);
    atomicAdd(cnt + N + jInd[e], 1);
  }
}
__global__ __launch_bounds__(256) void k_scan1(const int* __restrict__ cnt, int n2,
                                               int* __restrict__ partial, int* __restrict__ bsum) {
  __shared__ int sdata[256];
  int tid = threadIdx.x;
  int base = blockIdx.x * 1024 + tid * 4;
  int v[4], ts = 0;
#pragma unroll
  for (int c = 0; c < 4; ++c) { v[c] = (base + c < n2) ? cnt[base + c] : 0; ts += v[c]; }
  sdata[tid] = ts;
  __syncthreads();
  for (int o = 1; o < 256; o <<= 1) {
    int x = (tid >= o) ? sdata[tid - o] : 0;
    __syncthreads();
    sdata[tid] += x;
    __syncthreads();
  }
  int run = sdata[tid] - ts;
#pragma unroll
  for (int c = 0; c < 4; ++c) {
    if (base + c < n2) partial[base + c] = run;
    run += v[c];
  }
  if (tid == 255) bsum[blockIdx.x] = sdata[255];
}
__global__ __launch_bounds__(256) void k_scan2(int* __restrict__ bsum, int nb) {
  __shared__ int sdata[256];
  int tid = threadIdx.x;
  int v = (tid < nb) ? bsum[tid] : 0;
  sdata[tid] = v;
  __syncthreads();
  for (int o = 1; o < 256; o <<= 1) {
    int x = (tid >= o) ? sdata[tid - o] : 0;
    __syncthreads();
    sdata[tid] += x;
    __syncthreads();
  }
  if (tid < nb) bsum[tid] = sdata[tid] - v;
}
__global__ __launch_bounds__(256) void k_scan3(const int* __restrict__ partial,
                                               const int* __restrict__ bsum,
                                               int* __restrict__ offs, int* __restrict__ cursor, int n2) {
  int i = blockIdx.x * 256 + threadIdx.x;
  if (i < n2) {
    int o = partial[i] + bsum[i >> 10];
    offs[i] = o;
    cursor[i] = o;
  }
}
__global__ __launch_bounds__(256) void k_fill(const int* __restrict__ iInd,
                                              const int* __restrict__ jInd,
                                              int* __restrict__ cursor, int* __restrict__ csr,
                                              long long E, int N) {
  long long e = (long long)blockIdx.x * 256 + threadIdx.x;
  if (e < E) {
    int p1 = atomicAdd(cursor + iInd[e], 1);
    csr[p1] = (int)e;
    int p2 = atomicAdd(cursor + N + jInd[e], 1);
    csr[p2] = (int)e;
  }
}

// ---- sample opening stats ----
__global__ __launch_bounds__(256) void k_s_open(
    const float* __restrict__ X, const unsigned short* __restrict__ K1,
    long long W, int stride, double* __restrict__ sOut) {
  __shared__ __align__(16) float xf[64][68];
  __shared__ __align__(16) unsigned short at[64][72];
  int t = threadIdx.x, wave = t >> 6, lane = t & 63;
  int oc = wave * 16 + (lane & 15), g = lane >> 4, r = t >> 2, q = t & 3;
  long long g0 = (long long)blockIdx.x * stride * 64;
  int i4 = (t & 15) * 4, c0i = t >> 4;
#pragma unroll
  for (int p = 0; p < 4; ++p) {
    f32x4 vv = {};
    long long it0 = g0 + i4;
    if (it0 < W) vv = *(const f32x4*)(X + (long long)(c0i + p * 16) * W + it0);
    *(f32x4*)&xf[c0i + p * 16][i4] = vv;
  }
  __syncthreads();
#pragma unroll
  for (int cc = 0; cc < 16; ++cc) { int c = q + cc * 4; at[r][c] = f2bf(xf[c][r]); }
  __syncthreads();
  short8 b0 = *(const short8*)(K1 + oc * 64 + g * 8);
  short8 b1 = *(const short8*)(K1 + oc * 64 + 32 + g * 8);
  f32x4 acc[4] = {};
  mfma64t(at, b0, b1, lane, g, acc);
  float ssum = 0.f, ssq = 0.f;
#pragma unroll
  for (int it = 0; it < 4; ++it)
#pragma unroll
    for (int rg = 0; rg < 4; ++rg) {
      int row = it * 16 + 4 * g + rg;
      float v = acc[it][rg];
      if (g0 + row < W) { ssum += v; ssq += v * v; }
    }
  stats_reduce(ssum, ssq, sOut);
}

// ---- fused opening ----
template<int TILES>
__global__ __launch_bounds__(256) void k_open_f(
    const float* __restrict__ X, const unsigned short* __restrict__ K1,
    const unsigned short* __restrict__ K2, const double* __restrict__ s0, long long c0cnt,
    unsigned short* __restrict__ Y, long long W) {
  __shared__ __align__(16) float xf[64][66];
  __shared__ __align__(16) unsigned short zA[64][72];
  __shared__ __align__(16) unsigned short zB[64][72];
  int t = threadIdx.x, wave = t >> 6, lane = t & 63;
  int oc = wave * 16 + (lane & 15), g = lane >> 4, r = t >> 2, q = t & 3;
  long long g0 = (long long)blockIdx.x * (64 * TILES);
  float mu, rs;
  ln_params(s0, c0cnt, mu, rs);
  short8 b10 = *(const short8*)(K1 + oc * 64 + g * 8);
  short8 b11 = *(const short8*)(K1 + oc * 64 + 32 + g * 8);
  short8 b20 = *(const short8*)(K2 + oc * 64 + g * 8);
  short8 b21 = *(const short8*)(K2 + oc * 64 + 32 + g * 8);
  int i4 = (t & 15) * 4, c0i = t >> 4;
  f32x4 v[4];
  {
    long long it0 = g0 + i4;
#pragma unroll
    for (int p = 0; p < 4; ++p) {
      f32x4 vv = {};
      if (it0 < W) vv = *(const f32x4*)(X + (long long)(c0i + p * 16) * W + it0);
      v[p] = vv;
    }
  }
  for (int tt = 0; tt < TILES; ++tt) {
    long long base = g0 + tt * 64;
    f32x4 nv[4];
    if (tt + 1 < TILES) {
      long long itn = base + 64 + i4;
#pragma unroll
      for (int p = 0; p < 4; ++p) {
        f32x4 vv = {};
        if (itn < W) vv = *(const f32x4*)(X + (long long)(c0i + p * 16) * W + itn);
        nv[p] = vv;
      }
    }
#pragma unroll
    for (int p = 0; p < 4; ++p) {
      int c = c0i + p * 16;
#pragma unroll
      for (int k = 0; k < 4; ++k) xf[c][i4 + k] = v[p][k];
    }
    bar_lds();
    f32x4 a1[4] = {};
#pragma unroll
    for (int it = 0; it < 4; ++it) {
      int item = it * 16 + (lane & 15);
      float fa[16];
#pragma unroll
      for (int j = 0; j < 8; ++j) {
        fa[j] = xf[g * 8 + j][item];
        fa[8 + j] = xf[32 + g * 8 + j][item];
      }
      short8 a0 = pk8(fa), a1f = pk8(fa + 8);
      a1[it] = __builtin_amdgcn_mfma_f32_16x16x32_bf16(a0, b10, a1[it], 0, 0, 0);
      a1[it] = __builtin_amdgcn_mfma_f32_16x16x32_bf16(a1f, b11, a1[it], 0, 0, 0);
    }
#pragma unroll
    for (int it = 0; it < 4; ++it) {
      float r0 = fmaxf((a1[it][0] - mu) * rs, 0.f);
      float r1 = fmaxf((a1[it][1] - mu) * rs, 0.f);
      float r2 = fmaxf((a1[it][2] - mu) * rs, 0.f);
      float r3 = fmaxf((a1[it][3] - mu) * rs, 0.f);
      unsigned p01 = cvt2(r0, r1), p23 = cvt2(r2, r3);
      int row = it * 16 + 4 * g;
      zA[row + 0][oc] = (unsigned short)(p01 & 0xffff);
      zA[row + 1][oc] = (unsigned short)(p01 >> 16);
      zA[row + 2][oc] = (unsigned short)(p23 & 0xffff);
      zA[row + 3][oc] = (unsigned short)(p23 >> 16);
    }
    bar_lds();
    f32x4 a2[4] = {};
    mfma64t(zA, b20, b21, lane, g, a2);
#pragma unroll
    for (int it = 0; it < 4; ++it) {
      unsigned p01 = cvt2(a2[it][0], a2[it][1]), p23 = cvt2(a2[it][2], a2[it][3]);
      int row = it * 16 + 4 * g;
      zB[row + 0][oc] = (unsigned short)(p01 & 0xffff);
      zB[row + 1][oc] = (unsigned short)(p01 >> 16);
      zB[row + 2][oc] = (unsigned short)(p23 & 0xffff);
      zB[row + 3][oc] = (unsigned short)(p23 >> 16);
    }
    bar_lds();
    long long gi = base + r;
    if (gi < W) {
      *(short8*)(Y + gi * 64 + q * 16) = *(const short8*)&zB[r][q * 16];
      *(short8*)(Y + gi * 64 + q * 16 + 8) = *(const short8*)&zB[r][q * 16 + 8];
    }
#pragma unroll
    for (int p = 0; p < 4; ++p) v[p] = nv[p];
  }
}

// ---- sample layer-edge stats pass 1 ----
__global__ __launch_bounds__(256) void k_s_edge1(
    const unsigned short* __restrict__ xnt, const unsigned short* __restrict__ xe,
    const int* __restrict__ iInd, const int* __restrict__ jInd,
    const unsigned short* __restrict__ K1, unsigned short* __restrict__ z1s,
    long long E, int stride, double* __restrict__ sOut) {
  __shared__ __align__(16) unsigned short feat[64][200];
  auto zA = (unsigned short (*)[72])(&feat[0][0]);
  int t = threadIdx.x, wave = t >> 6, lane = t & 63;
  int oc = wave * 16 + (lane & 15), g = lane >> 4, r = t >> 2, q = t & 3;
  long long e0 = (long long)blockIdx.x * stride * 64;
  long long e = e0 + r;
  long long vi = 0, vj = 0;
  if (e < E) { vi = iInd[e]; vj = jInd[e]; }
  short8 xi0 = {}, xi1 = {}, xj0 = {}, xj1 = {}, m0 = {}, m1 = {};
  {
    const unsigned short* pi = xnt + vi * 64 + q * 16;
    const unsigned short* pj = xnt + vj * 64 + q * 16;
    xi0 = *(const short8*)pi; xi1 = *(const short8*)(pi + 8);
    xj0 = *(const short8*)pj; xj1 = *(const short8*)(pj + 8);
    if (e < E) {
      const unsigned short* pe = xe + e * 64 + q * 16;
      m0 = *(const short8*)pe; m1 = *(const short8*)(pe + 8);
    }
  }
  float fi[16], fg[16];
#pragma unroll
  for (int c = 0; c < 8; ++c) {
    float a0 = bf2f_s(xi0[c]), b0v = bf2f_s(xj0[c]);
    float a1 = bf2f_s(xi1[c]), b1v = bf2f_s(xj1[c]);
    fi[c] = 0.5f * (a0 + b0v); fi[8 + c] = 0.5f * (a1 + b1v);
    fg[c] = a0 - b0v;          fg[8 + c] = a1 - b1v;
  }
  *(short8*)&feat[r][q * 16]           = pk8(fi);
  *(short8*)&feat[r][q * 16 + 8]       = pk8(fi + 8);
  *(short8*)&feat[r][64 + q * 16]      = m0;
  *(short8*)&feat[r][64 + q * 16 + 8]  = m1;
  *(short8*)&feat[r][128 + q * 16]     = pk8(fg);
  *(short8*)&feat[r][128 + q * 16 + 8] = pk8(fg + 8);
  __syncthreads();
  short8 bfr[6];
#pragma unroll
  for (int k = 0; k < 6; ++k) bfr[k] = *(const short8*)(K1 + oc * 192 + k * 32 + g * 8);
  f32x4 acc[4] = {};
  mfma192(feat, bfr, lane, g, acc);
  __syncthreads();
  float ssum = 0.f, ssq = 0.f;
#pragma unroll
  for (int it = 0; it < 4; ++it)
#pragma unroll
    for (int rg = 0; rg < 4; ++rg) {
      int row = it * 16 + 4 * g + rg;
      float v = acc[it][rg];
      if (e0 + row < E) { ssum += v; ssq += v * v; }
      zA[row][oc] = f2bf(v);
    }
  __syncthreads();
  if (e < E) {
    unsigned short* p = z1s + ((long long)blockIdx.x * 64 + r) * 64 + q * 16;
    *(short8*)p = *(const short8*)&zA[r][q * 16];
    *(short8*)(p + 8) = *(const short8*)&zA[r][q * 16 + 8];
  }
  stats_reduce(ssum, ssq, sOut);
}

// ---- sample layer-edge stats pass 2 ----
__global__ __launch_bounds__(256) void k_s_edge2(
    const unsigned short* __restrict__ z1s, const unsigned short* __restrict__ K2,
    const double* __restrict__ s1, long long c1, long long E, int stride,
    double* __restrict__ sOut) {
  __shared__ __align__(16) unsigned short at[64][72];
  int t = threadIdx.x, wave = t >> 6, lane = t & 63;
  int oc = wave * 16 + (lane & 15), g = lane >> 4, r = t >> 2, q = t & 3;
  long long e0 = (long long)blockIdx.x * stride * 64;
  float mu1, rs1;
  ln_params(s1, c1, mu1, rs1);
  const unsigned short* p = z1s + ((long long)blockIdx.x * 64 + r) * 64 + q * 16;
  short8 v0 = *(const short8*)p, v1 = *(const short8*)(p + 8);
  float fw[16];
#pragma unroll
  for (int c = 0; c < 8; ++c) {
    fw[c] = fmaxf((bf2f_s(v0[c]) - mu1) * rs1, 0.f);
    fw[8 + c] = fmaxf((bf2f_s(v1[c]) - mu1) * rs1, 0.f);
  }
  *(short8*)&at[r][q * 16] = pk8(fw);
  *(short8*)&at[r][q * 16 + 8] = pk8(fw + 8);
  __syncthreads();
  short8 b20 = *(const short8*)(K2 + oc * 64 + g * 8);
  short8 b21 = *(const short8*)(K2 + oc * 64 + 32 + g * 8);
  f32x4 acc[4] = {};
  mfma64t(at, b20, b21, lane, g, acc);
  float ssum = 0.f, ssq = 0.f;
#pragma unroll
  for (int it = 0; it < 4; ++it)
#pragma unroll
    for (int rg = 0; rg < 4; ++rg) {
      int row = it * 16 + 4 * g + rg;
      float v = acc[it][rg];
      if (e0 + row < E) { ssum += v; ssq += v * v; }
    }
  stats_reduce(ssum, ssq, sOut);
}

// ---- node gather + feat build (used by k_s_node) ----
__device__ __forceinline__ void node_gather_feat(
    const unsigned short* xet, const unsigned short* xnt,
    const int* cntA, const int* offs, const int* csr,
    int n, int N, int r, int q, unsigned short (*feat)[200],
    short8& x0, short8& x1) {
  f32x4 ai[4] = {}, aj[4] = {};
  x0 = short8{}; x1 = short8{};
  if (n < N) {
    for (int side = 0; side < 2; ++side) {
      int d = cntA[side * N + n], o = offs[side * N + n];
      f32x4* a = side ? aj : ai;
      int k = 0;
      for (; k + 4 <= d; k += 4) {
        int ea = csr[o + k], eb = csr[o + k + 1], ec = csr[o + k + 2], ed = csr[o + k + 3];
        const unsigned short* pa = xet + (long long)ea * 64 + q * 16;
        const unsigned short* pb = xet + (long long)eb * 64 + q * 16;
        const unsigned short* pc = xet + (long long)ec * 64 + q * 16;
        const unsigned short* pd = xet + (long long)ed * 64 + q * 16;
        short8 va0 = *(const short8*)pa, va1 = *(const short8*)(pa + 8);
        short8 vb0 = *(const short8*)pb, vb1 = *(const short8*)(pb + 8);
        short8 vc0 = *(const short8*)pc, vc1 = *(const short8*)(pc + 8);
        short8 vd0 = *(const short8*)pd, vd1 = *(const short8*)(pd + 8);
#pragma unroll
        for (int c = 0; c < 8; ++c) {
          a[c >> 2][c & 3]       += bf2f_s(va0[c]) + bf2f_s(vb0[c]) + bf2f_s(vc0[c]) + bf2f_s(vd0[c]);
          a[2 + (c >> 2)][c & 3] += bf2f_s(va1[c]) + bf2f_s(vb1[c]) + bf2f_s(vc1[c]) + bf2f_s(vd1[c]);
        }
      }
      for (; k < d; ++k) {
        int e = csr[o + k];
        const unsigned short* pr = xet + (long long)e * 64 + q * 16;
        short8 v0 = *(const short8*)pr;
        short8 v1 = *(const short8*)(pr + 8);
#pragma unroll
        for (int c = 0; c < 8; ++c) {
          a[c >> 2][c & 3]       += bf2f_s(v0[c]);
          a[2 + (c >> 2)][c & 3] += bf2f_s(v1[c]);
        }
      }
    }
    const unsigned short* px = xnt + (long long)n * 64 + q * 16;
    x0 = *(const short8*)px; x1 = *(const short8*)(px + 8);
  }
  float fa[16], fd[16];
#pragma unroll
  for (int c = 0; c < 8; ++c) {
    float sa = ai[c >> 2][c & 3], sb = aj[c >> 2][c & 3];
    float sa1 = ai[2 + (c >> 2)][c & 3], sb1 = aj[2 + (c >> 2)][c & 3];
    fa[c] = 0.5f * (sa + sb);  fa[8 + c] = 0.5f * (sa1 + sb1);
    fd[c] = sa - sb;           fd[8 + c] = sa1 - sb1;
  }
  *(short8*)&feat[r][q * 16]           = pk8(fa);
  *(short8*)&feat[r][q * 16 + 8]       = pk8(fa + 8);
  *(short8*)&feat[r][64 + q * 16]      = pk8(fd);
  *(short8*)&feat[r][64 + q * 16 + 8]  = pk8(fd + 8);
  *(short8*)&feat[r][128 + q * 16]     = x0;
  *(short8*)&feat[r][128 + q * 16 + 8] = x1;
}

// ---- sample node stats ----
__global__ __launch_bounds__(256) void k_s_node(
    const unsigned short* __restrict__ xet, const unsigned short* __restrict__ xnt,
    const int* __restrict__ cntA, const int* __restrict__ offs, const int* __restrict__ csr,
    const unsigned short* __restrict__ K1, int N, int stride, double* __restrict__ sOut) {
  __shared__ __align__(16) unsigned short feat[64][200];
  int t = threadIdx.x, wave = t >> 6, lane = t & 63;
  int oc = wave * 16 + (lane & 15), g = lane >> 4, r = t >> 2, q = t & 3;
  int n0b = blockIdx.x * stride * 64;
  short8 x0, x1;
  node_gather_feat(xet, xnt, cntA, offs, csr, n0b + r, N, r, q, feat, x0, x1);
  __syncthreads();
  short8 bfr[6];
#pragma unroll
  for (int k = 0; k < 6; ++k) bfr[k] = *(const short8*)(K1 + oc * 192 + k * 32 + g * 8);
  f32x4 acc[4] = {};
  mfma192(feat, bfr, lane, g, acc);
  float ssum = 0.f, ssq = 0.f;
#pragma unroll
  for (int it = 0; it < 4; ++it)
#pragma unroll
    for (int rg = 0; rg < 4; ++rg) {
      int row = it * 16 + 4 * g + rg;
      float v = acc[it][rg];
      if (n0b + row < N) { ssum += v; ssq += v * v; }
    }
  stats_reduce(ssum, ssq, sOut);
}

// ---- wave-independent fused edge layer (R11 config: KE1+KE2 in LDS, 88 VGPR) ----
template<int WOUT, int ITERS>
__global__ __launch_bounds__(256) void k_edge_w(
    const unsigned short* __restrict__ xnt, const unsigned short* __restrict__ xeIn,
    unsigned short* __restrict__ xeOut,
    const int* __restrict__ iInd, const int* __restrict__ jInd,
    const unsigned short* __restrict__ K1, const unsigned short* __restrict__ K2,
    const double* __restrict__ s1, long long c1,
    const double* __restrict__ s2, long long c2,
    long long E, float* __restrict__ out1) {
  __shared__ __align__(16) unsigned short kw1[64 * 200];
  __shared__ __align__(16) unsigned short kw2[64 * 72];
  __shared__ __align__(16) unsigned short slmem[4 * 3328];
  int t = threadIdx.x;
  int w = t >> 6, lane = t & 63;
  int r16 = lane & 15, h = lane >> 4;
  unsigned short* sl = slmem + w * 3328;
  // stage weights (once; the only block barrier)
  {
    int oc = t >> 2, seg = t & 3;
    const unsigned short* s1p = K1 + oc * 192 + seg * 48;
    unsigned short* d1 = kw1 + oc * 200 + seg * 48;
#pragma unroll
    for (int p = 0; p < 6; ++p) *(short8*)(d1 + p * 8) = *(const short8*)(s1p + p * 8);
    const unsigned short* s2p = K2 + oc * 64 + seg * 16;
    unsigned short* d2 = kw2 + oc * 72 + seg * 16;
    *(short8*)(d2) = *(const short8*)(s2p);
    *(short8*)(d2 + 8) = *(const short8*)(s2p + 8);
  }
  __syncthreads();
  float mu1, rs1, mu2, rs2;
  ln_params(s1, c1, mu1, rs1);
  ln_params(s2, c2, mu2, rs2);
  long long eBase = (long long)blockIdx.x * (64 * ITERS) + (long long)w * (16 * ITERS);
  long long vi[ITERS], vj[ITERS];
#pragma unroll
  for (int it = 0; it < ITERS; ++it) {
    long long e = eBase + it * 16 + r16;
    bool ok = e < E;
    vi[it] = ok ? iInd[e] : 0;
    vj[it] = ok ? jInd[e] : 0;
  }
  // prefetch iter 0
  short8 ci0, ci1, cj0, cj1, xo0 = {}, xo1 = {};
  {
    const unsigned short* pi = xnt + vi[0] * 64 + h * 16;
    const unsigned short* pj = xnt + vj[0] * 64 + h * 16;
    ci0 = *(const short8*)pi; ci1 = *(const short8*)(pi + 8);
    cj0 = *(const short8*)pj; cj1 = *(const short8*)(pj + 8);
    long long e = eBase + r16;
    long long ec = (e < E) ? e : 0;
    const unsigned short* pe = xeIn + ec * 64 + h * 16;
    xo0 = *(const short8*)pe; xo1 = *(const short8*)(pe + 8);
  }
  for (int it = 0; it < ITERS; ++it) {
    long long e = eBase + it * 16 + r16;
    // issue next iter's loads (in flight across whole compute; no barrier drains them)
    short8 ni0 = {}, ni1 = {}, nj0 = {}, nj1 = {}, nx0 = {}, nx1 = {};
    if (it + 1 < ITERS) {
      const unsigned short* pi = xnt + vi[it + 1] * 64 + h * 16;
      const unsigned short* pj = xnt + vj[it + 1] * 64 + h * 16;
      ni0 = *(const short8*)pi; ni1 = *(const short8*)(pi + 8);
      nj0 = *(const short8*)pj; nj1 = *(const short8*)(pj + 8);
      long long en = eBase + (it + 1) * 16 + r16;
      long long ec = (en < E) ? en : 0;
      const unsigned short* pe = xeIn + ec * 64 + h * 16;
      nx0 = *(const short8*)pe; nx1 = *(const short8*)(pe + 8);
    }
    float fi[16], fg[16];
#pragma unroll
    for (int c = 0; c < 8; ++c) {
      float a0 = bf2f_s(ci0[c]), b0v = bf2f_s(cj0[c]);
      float a1 = bf2f_s(ci1[c]), b1v = bf2f_s(cj1[c]);
      fi[c] = 0.5f * (a0 + b0v); fi[8 + c] = 0.5f * (a1 + b1v);
      fg[c] = a0 - b0v;          fg[8 + c] = a1 - b1v;
    }
    wait_lds();  // prior iter's slice reads done before overwrite
    {
      unsigned short* fr = sl + r16 * 200 + h * 16;
      *(short8*)(fr)        = pk8(fi);
      *(short8*)(fr + 8)    = pk8(fi + 8);
      *(short8*)(fr + 64)   = xo0;
      *(short8*)(fr + 72)   = xo1;
      *(short8*)(fr + 128)  = pk8(fg);
      *(short8*)(fr + 136)  = pk8(fg + 8);
    }
    wait_lds();  // feat visible to this wave's lanes
    short8 a1f[6];
#pragma unroll
    for (int k = 0; k < 6; ++k)
      a1f[k] = *(const short8*)(sl + r16 * 200 + k * 32 + h * 8);
    f32x4 acc[4] = {};
#pragma unroll
    for (int og = 0; og < 4; ++og)
#pragma unroll
      for (int k = 0; k < 6; ++k) {
        short8 b = *(const short8*)(kw1 + (og * 16 + r16) * 200 + k * 32 + h * 8);
        acc[og] = __builtin_amdgcn_mfma_f32_16x16x32_bf16(a1f[k], b, acc[og], 0, 0, 0);
      }
#pragma unroll
    for (int og = 0; og < 4; ++og) {
      float r0 = fmaxf((acc[og][0] - mu1) * rs1, 0.f);
      float r1 = fmaxf((acc[og][1] - mu1) * rs1, 0.f);
      float r2 = fmaxf((acc[og][2] - mu1) * rs1, 0.f);
      float r3 = fmaxf((acc[og][3] - mu1) * rs1, 0.f);
      unsigned p01 = cvt2(r0, r1), p23 = cvt2(r2, r3);
      int colz = og * 16 + r16;
      sl[(h * 4 + 0) * 72 + colz] = (unsigned short)(p01 & 0xffff);
      sl[(h * 4 + 1) * 72 + colz] = (unsigned short)(p01 >> 16);
      sl[(h * 4 + 2) * 72 + colz] = (unsigned short)(p23 & 0xffff);
      sl[(h * 4 + 3) * 72 + colz] = (unsigned short)(p23 >> 16);
    }
    wait_lds();
    short8 a20 = *(const short8*)(sl + r16 * 72 + h * 8);
    short8 a21 = *(const short8*)(sl + r16 * 72 + 32 + h * 8);
    f32x4 acc2[4] = {};
#pragma unroll
    for (int og = 0; og < 4; ++og) {
      short8 b0 = *(const short8*)(kw2 + (og * 16 + r16) * 72 + h * 8);
      short8 b1 = *(const short8*)(kw2 + (og * 16 + r16) * 72 + 32 + h * 8);
      acc2[og] = __builtin_amdgcn_mfma_f32_16x16x32_bf16(a20, b0, acc2[og], 0, 0, 0);
      acc2[og] = __builtin_amdgcn_mfma_f32_16x16x32_bf16(a21, b1, acc2[og], 0, 0, 0);
    }
#pragma unroll
    for (int og = 0; og < 4; ++og) {
      unsigned p01 = cvt2(acc2[og][0], acc2[og][1]), p23 = cvt2(acc2[og][2], acc2[og][3]);
      int colz = og * 16 + r16;
      sl[1152 + (h * 4 + 0) * 72 + colz] = (unsigned short)(p01 & 0xffff);
      sl[1152 + (h * 4 + 1) * 72 + colz] = (unsigned short)(p01 >> 16);
      sl[1152 + (h * 4 + 2) * 72 + colz] = (unsigned short)(p23 & 0xffff);
      sl[1152 + (h * 4 + 3) * 72 + colz] = (unsigned short)(p23 >> 16);
    }
    wait_lds();
    short8 z0 = *(const short8*)(sl + 1152 + r16 * 72 + h * 16);
    short8 z1 = *(const short8*)(sl + 1152 + r16 * 72 + h * 16 + 8);
    float fo[16];
#pragma unroll
    for (int c = 0; c < 8; ++c) {
      fo[c]     = bf2f_s(xo0[c]) + HSTEP * ((bf2f_s(z0[c]) - mu2) * rs2);
      fo[8 + c] = bf2f_s(xo1[c]) + HSTEP * ((bf2f_s(z1[c]) - mu2) * rs2);
    }
    if constexpr (!WOUT) {
      if (e < E) {
        unsigned short* po = xeOut + e * 64 + h * 16;
        *(short8*)po = pk8(fo);
        *(short8*)(po + 8) = pk8(fo + 8);
      }
    } else {
      float* sf = (float*)sl;
#pragma unroll
      for (int p = 0; p < 4; ++p) {
        f32x4 vq = { fo[p * 4], fo[p * 4 + 1], fo[p * 4 + 2], fo[p * 4 + 3] };
        *(f32x4*)(sf + r16 * 68 + h * 16 + p * 4) = vq;
      }
      wait_lds();
#pragma unroll
      for (int p = 0; p < 16; ++p) {
        int c = h + 4 * p;
        float vv = sf[r16 * 68 + c];
        if (e < E) out1[(long long)c * E + e] = vv;
      }
    }
    ci0 = ni0; ci1 = ni1; cj0 = nj0; cj1 = nj1; xo0 = nx0; xo1 = nx1;
  }
}

// ---- wave-independent fused node layer (R12 config, kept: saved ~28 us) ----
template<int CLOSE>
__global__ __launch_bounds__(256) void k_node_w(
    const unsigned short* __restrict__ xet, unsigned short* xnt,
    const int* __restrict__ cntA, const int* __restrict__ offs, const int* __restrict__ csr,
    const unsigned short* __restrict__ K1, const unsigned short* __restrict__ K2,
    const unsigned short* __restrict__ Kc,
    const double* __restrict__ s3, long long c3,
    int N, float* __restrict__ out0) {
  __shared__ __align__(16) unsigned short kw1[64 * 196];
  __shared__ __align__(16) unsigned short slmem[4 * 3456];
  int t = threadIdx.x, w = t >> 6, lane = t & 63;
  int r16 = lane & 15, h = lane >> 4;
  unsigned short* sl = slmem + w * 3456;
  {
    int oc = t >> 2, seg = t & 3;
    const unsigned short* s1p = K1 + oc * 192 + seg * 48;
    unsigned short* d1 = kw1 + oc * 196 + seg * 48;
#pragma unroll
    for (int p = 0; p < 6; ++p) *(short8*)(d1 + p * 8) = *(const short8*)(s1p + p * 8);
  }
  short8 b20r[4], b21r[4], bc0r[4], bc1r[4];
#pragma unroll
  for (int og = 0; og < 4; ++og) {
    int oc = og * 16 + r16;
    b20r[og] = *(const short8*)(K2 + oc * 64 + h * 8);
    b21r[og] = *(const short8*)(K2 + oc * 64 + 32 + h * 8);
    if constexpr (CLOSE) {
      bc0r[og] = *(const short8*)(Kc + oc * 64 + h * 8);
      bc1r[og] = *(const short8*)(Kc + oc * 64 + 32 + h * 8);
    }
  }
  __syncthreads();
  float mu3, rs3;
  ln_params(s3, c3, mu3, rs3);
  int n = blockIdx.x * 64 + w * 16 + r16;
  f32x4 ai[4] = {}, aj[4] = {};
  short8 x0 = {}, x1 = {};
  if (n < N) {
    for (int side = 0; side < 2; ++side) {
      int d = cntA[side * N + n], o = offs[side * N + n];
      f32x4* a = side ? aj : ai;
      int k = 0;
      for (; k + 4 <= d; k += 4) {
        int ea = csr[o + k], eb = csr[o + k + 1], ec = csr[o + k + 2], ed = csr[o + k + 3];
        const unsigned short* pa = xet + (long long)ea * 64 + h * 16;
        const unsigned short* pb = xet + (long long)eb * 64 + h * 16;
        const unsigned short* pc = xet + (long long)ec * 64 + h * 16;
        const unsigned short* pd = xet + (long long)ed * 64 + h * 16;
        short8 va0 = *(const short8*)pa, va1 = *(const short8*)(pa + 8);
        short8 vb0 = *(const short8*)pb, vb1 = *(const short8*)(pb + 8);
        short8 vc0 = *(const short8*)pc, vc1 = *(const short8*)(pc + 8);
        short8 vd0 = *(const short8*)pd, vd1 = *(const short8*)(pd + 8);
#pragma unroll
        for (int c = 0; c < 8; ++c) {
          a[c >> 2][c & 3]       += bf2f_s(va0[c]) + bf2f_s(vb0[c]) + bf2f_s(vc0[c]) + bf2f_s(vd0[c]);
          a[2 + (c >> 2)][c & 3] += bf2f_s(va1[c]) + bf2f_s(vb1[c]) + bf2f_s(vc1[c]) + bf2f_s(vd1[c]);
        }
      }
      for (; k < d; ++k) {
        int e = csr[o + k];
        const unsigned short* pr = xet + (long long)e * 64 + h * 16;
        short8 v0 = *(const short8*)pr;
        short8 v1 = *(const short8*)(pr + 8);
#pragma unroll
        for (int c = 0; c < 8; ++c) {
          a[c >> 2][c & 3]       += bf2f_s(v0[c]);
          a[2 + (c >> 2)][c & 3] += bf2f_s(v1[c]);
        }
      }
    }
    const unsigned short* px = xnt + (long long)n * 64 + h * 16;
    x0 = *(const short8*)px; x1 = *(const short8*)(px + 8);
  }
  float fa[16], fd[16];
#pragma unroll
  for (int c = 0; c < 8; ++c) {
    float sa = ai[c >> 2][c & 3], sb = aj[c >> 2][c & 3];
    float sa1 = ai[2 + (c >> 2)][c & 3], sb1 = aj[2 + (c >> 2)][c & 3];
    fa[c] = 0.5f * (sa + sb);  fa[8 + c] = 0.5f * (sa1 + sb1);
    fd[c] = sa - sb;           fd[8 + c] = sa1 - sb1;
  }
  {
    unsigned short* fr = sl + r16 * 200 + h * 16;
    *(short8*)(fr)       = pk8(fa);
    *(short8*)(fr + 8)   = pk8(fa + 8);
    *(short8*)(fr + 64)  = pk8(fd);
    *(short8*)(fr + 72)  = pk8(fd + 8);
    *(short8*)(fr + 128) = x0;
    *(short8*)(fr + 136) = x1;
  }
  wait_lds();
  short8 a1f[6];
#pragma unroll
  for (int k = 0; k < 6; ++k)
    a1f[k] = *(const short8*)(sl + r16 * 200 + k * 32 + h * 8);
  f32x4 acc[4] = {};
#pragma unroll
  for (int og = 0; og < 4; ++og)
#pragma unroll
    for (int k = 0; k < 6; ++k) {
      short8 b = *(const short8*)(kw1 + (og * 16 + r16) * 196 + k * 32 + h * 8);
      acc[og] = __builtin_amdgcn_mfma_f32_16x16x32_bf16(a1f[k], b, acc[og], 0, 0, 0);
    }
#pragma unroll
  for (int og = 0; og < 4; ++og) {
    float r0 = fmaxf((acc[og][0] - mu3) * rs3, 0.f);
    float r1 = fmaxf((acc[og][1] - mu3) * rs3, 0.f);
    float r2 = fmaxf((acc[og][2] - mu3) * rs3, 0.f);
    float r3 = fmaxf((acc[og][3] - mu3) * rs3, 0.f);
    unsigned p01 = cvt2(r0, r1), p23 = cvt2(r2, r3);
    int colz = og * 16 + r16;
    sl[(h * 4 + 0) * 72 + colz] = (unsigned short)(p01 & 0xffff);
    sl[(h * 4 + 1) * 72 + colz] = (unsigned short)(p01 >> 16);
    sl[(h * 4 + 2) * 72 + colz] = (unsigned short)(p23 & 0xffff);
    sl[(h * 4 + 3) * 72 + colz] = (unsigned short)(p23 >> 16);
  }
  wait_lds();
  short8 a20 = *(const short8*)(sl + r16 * 72 + h * 8);
  short8 a21 = *(const short8*)(sl + r16 * 72 + 32 + h * 8);
  f32x4 acc2[4] = {};
#pragma unroll
  for (int og = 0; og < 4; ++og) {
    acc2[og] = __builtin_amdgcn_mfma_f32_16x16x32_bf16(a20, b20r[og], acc2[og], 0, 0, 0);
    acc2[og] = __builtin_amdgcn_mfma_f32_16x16x32_bf16(a21, b21r[og], acc2[og], 0, 0, 0);
  }
#pragma unroll
  for (int og = 0; og < 4; ++og) {
    unsigned p01 = cvt2(acc2[og][0], acc2[og][1]), p23 = cvt2(acc2[og][2], acc2[og][3]);
    int colz = og * 16 + r16;
    sl[1152 + (h * 4 + 0) * 72 + colz] = (unsigned short)(p01 & 0xffff);
    sl[1152 + (h * 4 + 1) * 72 + colz] = (unsigned short)(p01 >> 16);
    sl[1152 + (h * 4 + 2) * 72 + colz] = (unsigned short)(p23 & 0xffff);
    sl[1152 + (h * 4 + 3) * 72 + colz] = (unsigned short)(p23 >> 16);
  }
  wait_lds();
  short8 z0 = *(const short8*)(sl + 1152 + r16 * 72 + h * 16);
  short8 z1 = *(const short8*)(sl + 1152 + r16 * 72 + h * 16 + 8);
  float fw[16];
#pragma unroll
  for (int c = 0; c < 8; ++c) {
    fw[c]     = bf2f_s(x0[c]) + HSTEP * bf2f_s(z0[c]);
    fw[8 + c] = bf2f_s(x1[c]) + HSTEP * bf2f_s(z1[c]);
  }
  if constexpr (!CLOSE) {
    if (n < N) {
      unsigned short* po = xnt + (long long)n * 64 + h * 16;
      *(short8*)po = pk8(fw);
      *(short8*)(po + 8) = pk8(fw + 8);
    }
  } else {
    unsigned short* fws = sl + 2304 + r16 * 72 + h * 16;
    *(short8*)(fws) = pk8(fw);
    *(short8*)(fws + 8) = pk8(fw + 8);
    wait_lds();
    short8 a30 = *(const short8*)(sl + 2304 + r16 * 72 + h * 8);
    short8 a31 = *(const short8*)(sl + 2304 + r16 * 72 + 32 + h * 8);
    f32x4 acc3[4] = {};
#pragma unroll
    for (int og = 0; og < 4; ++og) {
      acc3[og] = __builtin_amdgcn_mfma_f32_16x16x32_bf16(a30, bc0r[og], acc3[og], 0, 0, 0);
      acc3[og] = __builtin_amdgcn_mfma_f32_16x16x32_bf16(a31, bc1r[og], acc3[og], 0, 0, 0);
    }
    float* sf = (float*)sl;
#pragma unroll
    for (int og = 0; og < 4; ++og)
#pragma unroll
      for (int rg = 0; rg < 4; ++rg)
        sf[(h * 4 + rg) * 68 + og * 16 + r16] = acc3[og][rg];
    wait_lds();
#pragma unroll
    for (int p = 0; p < 16; ++p) {
      int c = h + 4 * p;
      float vv = sf[r16 * 68 + c];
      if (n < N) out0[(long long)c * N + n] = vv;
    }
  }
}

extern "C" void kernel_launch(void* const* d_in, const int* in_sizes, int n_in,
                              void* d_out, int out_size, void* d_ws, size_t ws_size,
                              hipStream_t stream) {
  (void)n_in; (void)out_size; (void)ws_size;
  const float* xn  = (const float*)d_in[0];
  const float* xe  = (const float*)d_in[1];
  const int* iInd  = (const int*)d_in[2];
  const int* jInd  = (const int*)d_in[3];
  const float* K1N = (const float*)d_in[4];
  const float* K2N = (const float*)d_in[5];
  const float* K1E = (const float*)d_in[6];
  const float* K2E = (const float*)d_in[7];
  const float* KNc = (const float*)d_in[8];
  const float* KE1 = (const float*)d_in[9];
  const float* KE2 = (const float*)d_in[10];
  const float* KN1 = (const float*)d_in[11];
  const float* KN2 = (const float*)d_in[12];
  int N = in_sizes[0] / 64;
  long long E = in_sizes[2];
  float* out = (float*)d_out;

  long long Te = (E + 63) / 64;
  long long Tn = ((long long)N + 63) / 64;
  int gSe  = (int)((Te + 15) / 16);
  int gSn0 = (int)((Tn + 3) / 4);
  int gSn  = (int)((Tn + 7) / 8);
  int gOe  = (int)((Te + 3) / 4);
  int gOn  = (int)((Tn + 3) / 4);
  int gN1  = (int)Tn;
  int gEw  = (int)((E + 255) / 256);

  auto sampCnt = [](long long W, int stride) -> long long {
    long long T = (W + 63) / 64;
    long long ns = (T + stride - 1) / stride;
    long long lastTile = (ns - 1) * (long long)stride;
    long long lastItems = W - lastTile * 64;
    if (lastItems > 64) lastItems = 64;
    return ((ns - 1) * 64 + lastItems) * 64;
  };
  long long c0n = sampCnt(N, 4);
  long long c0e = sampCnt(E, 16);
  long long cSe = c0e;
  long long c3n = sampCnt(N, 8);

  size_t off = 0;
  auto carve = [&](size_t bytes) -> void* {
    void* p = (char*)d_ws + off;
    off += (bytes + 255) & ~(size_t)255;
    return p;
  };
  unsigned short* xnt = (unsigned short*)carve((size_t)N * 64 * 2);
  unsigned short* xeP = (unsigned short*)carve((size_t)E * 64 * 2);
  unsigned short* xeQ = (unsigned short*)carve((size_t)E * 64 * 2);
  unsigned short* z1s = (unsigned short*)carve((size_t)gSe * 64 * 64 * 2);
  double* stats = (double*)carve(16 * sizeof(double));
  unsigned short* kw = (unsigned short*)carve(86016 * 2);
  int n2 = 2 * N;
  int* cnt     = (int*)carve((size_t)n2 * 4);
  int* partial = (int*)carve((size_t)n2 * 4);
  int* offs    = (int*)carve((size_t)n2 * 4);
  int* cursor  = (int*)carve((size_t)n2 * 4);
  int* bsum    = (int*)carve(256 * 4);
  int* csr     = (int*)carve((size_t)2 * E * 4);

  unsigned short* kw_K1N = kw;
  unsigned short* kw_K2N = kw + 4096;
  unsigned short* kw_K1E = kw + 8192;
  unsigned short* kw_K2E = kw + 12288;
  unsigned short* kw_KNc = kw + 16384;
  unsigned short* kw_KE1 = kw + 20480;
  unsigned short* kw_KE2 = kw + 45056;
  unsigned short* kw_KN1 = kw + 53248;
  unsigned short* kw_KN2 = kw + 77824;

  hipMemsetAsync(stats, 0, 16 * sizeof(double), stream);
  hipMemsetAsync(cnt, 0, (size_t)n2 * 4, stream);
  k_cvt_all<<<336, 256, 0, stream>>>(K1N, K2N, K1E, K2E, KNc, KE1, KE2, KN1, KN2, kw);

  int gEth = (int)((E + 255) / 256);
  int nb = (n2 + 1023) / 1024;
  k_hist<<<gEth, 256, 0, stream>>>(iInd, jInd, cnt, E, N);
  k_scan1<<<nb, 256, 0, stream>>>(cnt, n2, partial, bsum);
  k_scan2<<<1, 256, 0, stream>>>(bsum, nb);
  k_scan3<<<(n2 + 255) / 256, 256, 0, stream>>>(partial, bsum, offs, cursor, n2);
  k_fill<<<gEth, 256, 0, stream>>>(iInd, jInd, cursor, csr, E, N);

  k_s_open<<<gSn0, 256, 0, stream>>>(xn, kw_K1N, N, 4, stats + 0);
  k_s_open<<<gSe, 256, 0, stream>>>(xe, kw_K1E, E, 16, stats + 2);
  k_open_f<4><<<gOn, 256, 0, stream>>>(xn, kw_K1N, kw_K2N, stats + 0, c0n, xnt, N);
  k_open_f<4><<<gOe, 256, 0, stream>>>(xe, kw_K1E, kw_K2E, stats + 2, c0e, xeP, E);

  float* out1 = out + (long long)64 * N;
  for (int L = 0; L < 2; ++L) {
    const unsigned short* xeL = (L == 0) ? xeP : xeQ;
    const unsigned short* ke1 = kw_KE1 + L * 12288;
    const unsigned short* ke2 = kw_KE2 + L * 4096;
    const unsigned short* kn1 = kw_KN1 + L * 12288;
    const unsigned short* kn2 = kw_KN2 + L * 4096;
    double* sb = stats + 4 + L * 6;
    k_s_edge1<<<gSe, 256, 0, stream>>>(xnt, xeL, iInd, jInd, ke1, z1s, E, 16, sb);
    k_s_edge2<<<gSe, 256, 0, stream>>>(z1s, ke2, sb, cSe, E, 16, sb + 2);
    if (L == 0)
      k_edge_w<0, 4><<<gEw, 256, 0, stream>>>(xnt, xeP, xeQ, iInd, jInd, ke1, ke2,
                                              sb, cSe, sb + 2, cSe, E, nullptr);
    else
      k_edge_w<1, 4><<<gEw, 256, 0, stream>>>(xnt, xeQ, nullptr, iInd, jInd, ke1, ke2,
                                              sb, cSe, sb + 2, cSe, E, out1);
    k_s_node<<<gSn, 256, 0, stream>>>(xeL, xnt, cnt, offs, csr, kn1, N, 8, sb + 4);
    if (L == 0)
      k_node_w<0><<<gN1, 256, 0, stream>>>(xeP, xnt, cnt, offs, csr, kn1, kn2, nullptr,
                                           sb + 4, c3n, N, nullptr);
    else
      k_node_w<1><<<gN1, 256, 0, stream>>>(xeQ, xnt, cnt, offs, csr, kn1, kn2, kw_KNc,
                                           sb + 4, c3n, N, out);
  }
}

// Round 14
// 421.475 us; speedup vs baseline: 1.0339x; 1.0339x over previous
//
#include <hip/hip_runtime.h>
#include <hip/hip_bf16.h>

#define HSTEP 0.1f
#define LN_EPS 1e-5f

typedef short short8 __attribute__((ext_vector_type(8)));
typedef float f32x4 __attribute__((ext_vector_type(4)));

__device__ __forceinline__ unsigned short f2bf(float f) {
  unsigned u = __builtin_bit_cast(unsigned, f);
  u += 0x7FFFu + ((u >> 16) & 1u);
  return (unsigned short)(u >> 16);
}
__device__ __forceinline__ float bf2f(unsigned short s) {
  unsigned u = ((unsigned)s) << 16;
  return __builtin_bit_cast(float, u);
}
__device__ __forceinline__ float bf2f_s(short s) { return bf2f((unsigned short)s); }

// Barrier that waits only on LDS ops (lgkmcnt), NOT on outstanding global
// loads/stores (vmcnt) — keeps cross-tile prefetch in flight.
__device__ __forceinline__ void bar_lds() {
  __builtin_amdgcn_sched_barrier(0);
  asm volatile("s_waitcnt lgkmcnt(0)" ::: "memory");
  __builtin_amdgcn_s_barrier();
  __builtin_amdgcn_sched_barrier(0);
}

__device__ __forceinline__ void stats_reduce(float ssum, float ssq, double* sOut) {
  for (int off = 32; off; off >>= 1) {
    ssum += __shfl_down(ssum, off);
    ssq  += __shfl_down(ssq, off);
  }
  __shared__ float rs_[4], rq_[4];
  int t = threadIdx.x;
  if ((t & 63) == 0) { rs_[t >> 6] = ssum; rq_[t >> 6] = ssq; }
  __syncthreads();
  if (t == 0) {
    atomicAdd(sOut + 0, (double)(rs_[0] + rs_[1] + rs_[2] + rs_[3]));
    atomicAdd(sOut + 1, (double)(rq_[0] + rq_[1] + rq_[2] + rq_[3]));
  }
}

__device__ __forceinline__ void ln_params(const double* sIn, long long cnt, float& mu, float& rs) {
  float cf = (float)cnt;
  float m = (float)sIn[0] / cf;
  float q = (float)sIn[1] / cf;
  mu = m;
  rs = rsqrtf(fmaxf(q - m * m, 0.f) + LN_EPS);
}

// MFMA helpers: A-tile rows=items, cols=channels
__device__ __forceinline__ void mfma192(const unsigned short (*feat)[200], const short8* bfr,
                                        int lane, int g, f32x4* acc) {
#pragma unroll
  for (int it = 0; it < 4; ++it)
#pragma unroll
    for (int k = 0; k < 6; ++k) {
      short8 a = *(const short8*)(&feat[it * 16 + (lane & 15)][k * 32 + g * 8]);
      acc[it] = __builtin_amdgcn_mfma_f32_16x16x32_bf16(a, bfr[k], acc[it], 0, 0, 0);
    }
}
__device__ __forceinline__ void mfma64t(const unsigned short (*at)[72], short8 b0, short8 b1,
                                        int lane, int g, f32x4* acc) {
#pragma unroll
  for (int it = 0; it < 4; ++it) {
    short8 a0 = *(const short8*)(&at[it * 16 + (lane & 15)][g * 8]);
    short8 a1 = *(const short8*)(&at[it * 16 + (lane & 15)][32 + g * 8]);
    acc[it] = __builtin_amdgcn_mfma_f32_16x16x32_bf16(a0, b0, acc[it], 0, 0, 0);
    acc[it] = __builtin_amdgcn_mfma_f32_16x16x32_bf16(a1, b1, acc[it], 0, 0, 0);
  }
}

// ---- all weights fp32 -> bf16 ----
__global__ __launch_bounds__(256) void k_cvt_all(
    const float* __restrict__ K1N, const float* __restrict__ K2N,
    const float* __restrict__ K1E, const float* __restrict__ K2E,
    const float* __restrict__ KNc, const float* __restrict__ KE1,
    const float* __restrict__ KE2, const float* __restrict__ KN1,
    const float* __restrict__ KN2, unsigned short* __restrict__ kw) {
  int i = blockIdx.x * 256 + threadIdx.x;
  if (i >= 86016) return;
  const float* s; int off;
  if (i < 4096)       { s = K1N; off = 0; }
  else if (i < 8192)  { s = K2N; off = 4096; }
  else if (i < 12288) { s = K1E; off = 8192; }
  else if (i < 16384) { s = K2E; off = 12288; }
  else if (i < 20480) { s = KNc; off = 16384; }
  else if (i < 45056) { s = KE1; off = 20480; }
  else if (i < 53248) { s = KE2; off = 45056; }
  else if (i < 77824) { s = KN1; off = 53248; }
  else                { s = KN2; off = 77824; }
  kw[i] = f2bf(s[i - off]);
}

// ==== CSR build ====
__global__ __launch_bounds__(256) void k_hist(const int* __restrict__ iInd,
                                              const int* __restrict__ jInd,
                                              int* __restrict__ cnt, long long E, int N) {
  long long e = (long long)blockIdx.x * 256 + threadIdx.x;
  if (e < E) {
    atomicAdd(cnt + iInd[e], 1);
    atomicAdd(cnt + N + jInd[e], 1);
  }
}
__global__ __launch_bounds__(256) void k_scan1(const int* __restrict__ cnt, int n2,
                                               int* __restrict__ partial, int* __restrict__ bsum) {
  __shared__ int sdata[256];
  int tid = threadIdx.x;
  int base = blockIdx.x * 1024 + tid * 4;
  int v[4], ts = 0;
#pragma unroll
  for (int c = 0; c < 4; ++c) { v[c] = (base + c < n2) ? cnt[base + c] : 0; ts += v[c]; }
  sdata[tid] = ts;
  __syncthreads();
  for (int o = 1; o < 256; o <<= 1) {
    int x = (tid >= o) ? sdata[tid - o] : 0;
    __syncthreads();
    sdata[tid] += x;
    __syncthreads();
  }
  int run = sdata[tid] - ts;
#pragma unroll
  for (int c = 0; c < 4; ++c) {
    if (base + c < n2) partial[base + c] = run;
    run += v[c];
  }
  if (tid == 255) bsum[blockIdx.x] = sdata[255];
}
__global__ __launch_bounds__(256) void k_scan2(int* __restrict__ bsum, int nb) {
  __shared__ int sdata[256];
  int tid = threadIdx.x;
  int v = (tid < nb) ? bsum[tid] : 0;
  sdata[tid] = v;
  __syncthreads();
  for (int o = 1; o < 256; o <<= 1) {
    int x = (tid >= o) ? sdata[tid - o] : 0;
    __syncthreads();
    sdata[tid] += x;
    __syncthreads();
  }
  if (tid < nb) bsum[tid] = sdata[tid] - v;
}
__global__ __launch_bounds__(256) void k_scan3(const int* __restrict__ partial,
                                               const int* __restrict__ bsum,
                                               int* __restrict__ offs, int* __restrict__ cursor, int n2) {
  int i = blockIdx.x * 256 + threadIdx.x;
  if (i < n2) {
    int o = partial[i] + bsum[i >> 10];
    offs[i] = o;
    cursor[i] = o;
  }
}
__global__ __launch_bounds__(256) void k_fill(const int* __restrict__ iInd,
                                              const int* __restrict__ jInd,
                                              int* __restrict__ cursor, int* __restrict__ csr,
                                              long long E, int N) {
  long long e = (long long)blockIdx.x * 256 + threadIdx.x;
  if (e < E) {
    int p1 = atomicAdd(cursor + iInd[e], 1);
    csr[p1] = (int)e;
    int p2 = atomicAdd(cursor + N + jInd[e], 1);
    csr[p2] = (int)e;
  }
}

// ---- sample opening stats ----
__global__ __launch_bounds__(256) void k_s_open(
    const float* __restrict__ X, const unsigned short* __restrict__ K1,
    long long W, int stride, double* __restrict__ sOut) {
  __shared__ __align__(16) float xf[64][68];
  __shared__ __align__(16) unsigned short at[64][72];
  int t = threadIdx.x, wave = t >> 6, lane = t & 63;
  int oc = wave * 16 + (lane & 15), g = lane >> 4, r = t >> 2, q = t & 3;
  long long g0 = (long long)blockIdx.x * stride * 64;
  int i4 = (t & 15) * 4, c0i = t >> 4;
#pragma unroll
  for (int p = 0; p < 4; ++p) {
    f32x4 vv = {};
    long long it0 = g0 + i4;
    if (it0 < W) vv = *(const f32x4*)(X + (long long)(c0i + p * 16) * W + it0);
    *(f32x4*)&xf[c0i + p * 16][i4] = vv;
  }
  __syncthreads();
#pragma unroll
  for (int cc = 0; cc < 16; ++cc) { int c = q + cc * 4; at[r][c] = f2bf(xf[c][r]); }
  __syncthreads();
  short8 b0 = *(const short8*)(K1 + oc * 64 + g * 8);
  short8 b1 = *(const short8*)(K1 + oc * 64 + 32 + g * 8);
  f32x4 acc[4] = {};
  mfma64t(at, b0, b1, lane, g, acc);
  float ssum = 0.f, ssq = 0.f;
#pragma unroll
  for (int it = 0; it < 4; ++it)
#pragma unroll
    for (int rg = 0; rg < 4; ++rg) {
      int row = it * 16 + 4 * g + rg;
      float v = acc[it][rg];
      if (g0 + row < W) { ssum += v; ssq += v * v; }
    }
  stats_reduce(ssum, ssq, sOut);
}

// ---- fused opening: fp32 chan-major -> K1 -> lnrelu(s0) -> K2 -> bf16 row-major ----
template<int TILES>
__global__ __launch_bounds__(256) void k_open_f(
    const float* __restrict__ X, const unsigned short* __restrict__ K1,
    const unsigned short* __restrict__ K2, const double* __restrict__ s0, long long c0cnt,
    unsigned short* __restrict__ Y, long long W) {
  __shared__ __align__(16) float xf[64][66];
  __shared__ __align__(16) unsigned short at[64][72];
  auto zA = at;
  auto zB = (unsigned short (*)[72])(&xf[0][0]);
  int t = threadIdx.x, wave = t >> 6, lane = t & 63;
  int oc = wave * 16 + (lane & 15), g = lane >> 4, r = t >> 2, q = t & 3;
  long long g0 = (long long)blockIdx.x * (64 * TILES);
  float mu, rs;
  ln_params(s0, c0cnt, mu, rs);
  short8 b10 = *(const short8*)(K1 + oc * 64 + g * 8);
  short8 b11 = *(const short8*)(K1 + oc * 64 + 32 + g * 8);
  short8 b20 = *(const short8*)(K2 + oc * 64 + g * 8);
  short8 b21 = *(const short8*)(K2 + oc * 64 + 32 + g * 8);
  int i4 = (t & 15) * 4, c0i = t >> 4;
  f32x4 v[4];
  {
    long long it0 = g0 + i4;
#pragma unroll
    for (int p = 0; p < 4; ++p) {
      f32x4 vv = {};
      if (it0 < W) vv = *(const f32x4*)(X + (long long)(c0i + p * 16) * W + it0);
      v[p] = vv;
    }
  }
  for (int tt = 0; tt < TILES; ++tt) {
    long long base = g0 + tt * 64;
    f32x4 nv[4];
    if (tt + 1 < TILES) {
      long long itn = base + 64 + i4;
#pragma unroll
      for (int p = 0; p < 4; ++p) {
        f32x4 vv = {};
        if (itn < W) vv = *(const f32x4*)(X + (long long)(c0i + p * 16) * W + itn);
        nv[p] = vv;
      }
    }
#pragma unroll
    for (int p = 0; p < 4; ++p) {
      int c = c0i + p * 16;
#pragma unroll
      for (int k = 0; k < 4; ++k) xf[c][i4 + k] = v[p][k];
    }
    bar_lds();
#pragma unroll
    for (int cc = 0; cc < 16; ++cc) { int c = q + cc * 4; at[r][c] = f2bf(xf[c][r]); }
    bar_lds();
    f32x4 a1[4] = {};
    mfma64t(at, b10, b11, lane, g, a1);
    bar_lds();  // at reads done before zA (=at) overwrite
#pragma unroll
    for (int it = 0; it < 4; ++it)
#pragma unroll
      for (int rg = 0; rg < 4; ++rg)
        zA[it * 16 + 4 * g + rg][oc] = f2bf(fmaxf((a1[it][rg] - mu) * rs, 0.f));
    bar_lds();
    f32x4 a2[4] = {};
    mfma64t(zA, b20, b21, lane, g, a2);
#pragma unroll
    for (int it = 0; it < 4; ++it)
#pragma unroll
      for (int rg = 0; rg < 4; ++rg)
        zB[it * 16 + 4 * g + rg][oc] = f2bf(a2[it][rg]);  // zB (=xf) disjoint from zA
    bar_lds();
    long long gi = base + r;
    if (gi < W) {
      *(short8*)(Y + gi * 64 + q * 16) = *(const short8*)&zB[r][q * 16];
      *(short8*)(Y + gi * 64 + q * 16 + 8) = *(const short8*)&zB[r][q * 16 + 8];
    }
    bar_lds();  // zB reads done before next xf write
#pragma unroll
    for (int p = 0; p < 4; ++p) v[p] = nv[p];
  }
}

// ---- sample layer-edge stats pass 1 ----
__global__ __launch_bounds__(256) void k_s_edge1(
    const unsigned short* __restrict__ xnt, const unsigned short* __restrict__ xe,
    const int* __restrict__ iInd, const int* __restrict__ jInd,
    const unsigned short* __restrict__ K1, unsigned short* __restrict__ z1s,
    long long E, int stride, double* __restrict__ sOut) {
  __shared__ __align__(16) unsigned short feat[64][200];
  auto zA = (unsigned short (*)[72])(&feat[0][0]);
  int t = threadIdx.x, wave = t >> 6, lane = t & 63;
  int oc = wave * 16 + (lane & 15), g = lane >> 4, r = t >> 2, q = t & 3;
  long long e0 = (long long)blockIdx.x * stride * 64;
  long long e = e0 + r;
  long long vi = 0, vj = 0;
  if (e < E) { vi = iInd[e]; vj = jInd[e]; }
  short8 xi0 = {}, xi1 = {}, xj0 = {}, xj1 = {}, m0 = {}, m1 = {};
  {
    const unsigned short* pi = xnt + vi * 64 + q * 16;
    const unsigned short* pj = xnt + vj * 64 + q * 16;
    xi0 = *(const short8*)pi; xi1 = *(const short8*)(pi + 8);
    xj0 = *(const short8*)pj; xj1 = *(const short8*)(pj + 8);
    if (e < E) {
      const unsigned short* pe = xe + e * 64 + q * 16;
      m0 = *(const short8*)pe; m1 = *(const short8*)(pe + 8);
    }
  }
  short8 i0, i1, gg0, gg1;
#pragma unroll
  for (int c = 0; c < 8; ++c) {
    float a0 = bf2f_s(xi0[c]), b0v = bf2f_s(xj0[c]);
    float a1 = bf2f_s(xi1[c]), b1v = bf2f_s(xj1[c]);
    i0[c]  = (short)f2bf(0.5f * (a0 + b0v));
    i1[c]  = (short)f2bf(0.5f * (a1 + b1v));
    gg0[c] = (short)f2bf(a0 - b0v);
    gg1[c] = (short)f2bf(a1 - b1v);
  }
  *(short8*)&feat[r][q * 16]           = i0;
  *(short8*)&feat[r][q * 16 + 8]       = i1;
  *(short8*)&feat[r][64 + q * 16]      = m0;
  *(short8*)&feat[r][64 + q * 16 + 8]  = m1;
  *(short8*)&feat[r][128 + q * 16]     = gg0;
  *(short8*)&feat[r][128 + q * 16 + 8] = gg1;
  __syncthreads();
  short8 bfr[6];
#pragma unroll
  for (int k = 0; k < 6; ++k) bfr[k] = *(const short8*)(K1 + oc * 192 + k * 32 + g * 8);
  f32x4 acc[4] = {};
  mfma192(feat, bfr, lane, g, acc);
  __syncthreads();
  float ssum = 0.f, ssq = 0.f;
#pragma unroll
  for (int it = 0; it < 4; ++it)
#pragma unroll
    for (int rg = 0; rg < 4; ++rg) {
      int row = it * 16 + 4 * g + rg;
      float v = acc[it][rg];
      if (e0 + row < E) { ssum += v; ssq += v * v; }
      zA[row][oc] = f2bf(v);
    }
  __syncthreads();
  if (e < E) {
    unsigned short* p = z1s + ((long long)blockIdx.x * 64 + r) * 64 + q * 16;
    *(short8*)p = *(const short8*)&zA[r][q * 16];
    *(short8*)(p + 8) = *(const short8*)&zA[r][q * 16 + 8];
  }
  stats_reduce(ssum, ssq, sOut);
}

// ---- sample layer-edge stats pass 2 ----
__global__ __launch_bounds__(256) void k_s_edge2(
    const unsigned short* __restrict__ z1s, const unsigned short* __restrict__ K2,
    const double* __restrict__ s1, long long c1, long long E, int stride,
    double* __restrict__ sOut) {
  __shared__ __align__(16) unsigned short at[64][72];
  int t = threadIdx.x, wave = t >> 6, lane = t & 63;
  int oc = wave * 16 + (lane & 15), g = lane >> 4, r = t >> 2, q = t & 3;
  long long e0 = (long long)blockIdx.x * stride * 64;
  float mu1, rs1;
  ln_params(s1, c1, mu1, rs1);
  const unsigned short* p = z1s + ((long long)blockIdx.x * 64 + r) * 64 + q * 16;
  short8 v0 = *(const short8*)p, v1 = *(const short8*)(p + 8);
  short8 w0, w1;
#pragma unroll
  for (int c = 0; c < 8; ++c) {
    w0[c] = (short)f2bf(fmaxf((bf2f_s(v0[c]) - mu1) * rs1, 0.f));
    w1[c] = (short)f2bf(fmaxf((bf2f_s(v1[c]) - mu1) * rs1, 0.f));
  }
  *(short8*)&at[r][q * 16] = w0;
  *(short8*)&at[r][q * 16 + 8] = w1;
  __syncthreads();
  short8 b20 = *(const short8*)(K2 + oc * 64 + g * 8);
  short8 b21 = *(const short8*)(K2 + oc * 64 + 32 + g * 8);
  f32x4 acc[4] = {};
  mfma64t(at, b20, b21, lane, g, acc);
  float ssum = 0.f, ssq = 0.f;
#pragma unroll
  for (int it = 0; it < 4; ++it)
#pragma unroll
    for (int rg = 0; rg < 4; ++rg) {
      int row = it * 16 + 4 * g + rg;
      float v = acc[it][rg];
      if (e0 + row < E) { ssum += v; ssq += v * v; }
    }
  stats_reduce(ssum, ssq, sOut);
}

// ---- node gather + feat build (shared) ----
__device__ __forceinline__ void node_gather_feat(
    const unsigned short* xet, const unsigned short* xnt,
    const int* cntA, const int* offs, const int* csr,
    int n, int N, int r, int q, unsigned short (*feat)[200],
    short8& x0, short8& x1) {
  f32x4 ai[4] = {}, aj[4] = {};
  x0 = short8{}; x1 = short8{};
  if (n < N) {
    for (int side = 0; side < 2; ++side) {
      int d = cntA[side * N + n], o = offs[side * N + n];
      f32x4* a = side ? aj : ai;
      int k = 0;
      for (; k + 4 <= d; k += 4) {
        int ea = csr[o + k], eb = csr[o + k + 1], ec = csr[o + k + 2], ed = csr[o + k + 3];
        const unsigned short* pa = xet + (long long)ea * 64 + q * 16;
        const unsigned short* pb = xet + (long long)eb * 64 + q * 16;
        const unsigned short* pc = xet + (long long)ec * 64 + q * 16;
        const unsigned short* pd = xet + (long long)ed * 64 + q * 16;
        short8 va0 = *(const short8*)pa, va1 = *(const short8*)(pa + 8);
        short8 vb0 = *(const short8*)pb, vb1 = *(const short8*)(pb + 8);
        short8 vc0 = *(const short8*)pc, vc1 = *(const short8*)(pc + 8);
        short8 vd0 = *(const short8*)pd, vd1 = *(const short8*)(pd + 8);
#pragma unroll
        for (int c = 0; c < 8; ++c) {
          a[c >> 2][c & 3]       += bf2f_s(va0[c]) + bf2f_s(vb0[c]) + bf2f_s(vc0[c]) + bf2f_s(vd0[c]);
          a[2 + (c >> 2)][c & 3] += bf2f_s(va1[c]) + bf2f_s(vb1[c]) + bf2f_s(vc1[c]) + bf2f_s(vd1[c]);
        }
      }
      for (; k < d; ++k) {
        int e = csr[o + k];
        const unsigned short* pr = xet + (long long)e * 64 + q * 16;
        short8 v0 = *(const short8*)pr;
        short8 v1 = *(const short8*)(pr + 8);
#pragma unroll
        for (int c = 0; c < 8; ++c) {
          a[c >> 2][c & 3]       += bf2f_s(v0[c]);
          a[2 + (c >> 2)][c & 3] += bf2f_s(v1[c]);
        }
      }
    }
    const unsigned short* px = xnt + (long long)n * 64 + q * 16;
    x0 = *(const short8*)px; x1 = *(const short8*)(px + 8);
  }
  short8 av0, av1, dv0, dv1;
#pragma unroll
  for (int c = 0; c < 8; ++c) {
    float sa = ai[c >> 2][c & 3], sb = aj[c >> 2][c & 3];
    av0[c] = (short)f2bf(0.5f * (sa + sb));
    dv0[c] = (short)f2bf(sa - sb);
    float sa1 = ai[2 + (c >> 2)][c & 3], sb1 = aj[2 + (c >> 2)][c & 3];
    av1[c] = (short)f2bf(0.5f * (sa1 + sb1));
    dv1[c] = (short)f2bf(sa1 - sb1);
  }
  *(short8*)&feat[r][q * 16]           = av0;
  *(short8*)&feat[r][q * 16 + 8]       = av1;
  *(short8*)&feat[r][64 + q * 16]      = dv0;
  *(short8*)&feat[r][64 + q * 16 + 8]  = dv1;
  *(short8*)&feat[r][128 + q * 16]     = x0;
  *(short8*)&feat[r][128 + q * 16 + 8] = x1;
}

// ---- sample node stats ----
__global__ __launch_bounds__(256) void k_s_node(
    const unsigned short* __restrict__ xet, const unsigned short* __restrict__ xnt,
    const int* __restrict__ cntA, const int* __restrict__ offs, const int* __restrict__ csr,
    const unsigned short* __restrict__ K1, int N, int stride, double* __restrict__ sOut) {
  __shared__ __align__(16) unsigned short feat[64][200];
  int t = threadIdx.x, wave = t >> 6, lane = t & 63;
  int oc = wave * 16 + (lane & 15), g = lane >> 4, r = t >> 2, q = t & 3;
  int n0b = blockIdx.x * stride * 64;
  short8 x0, x1;
  node_gather_feat(xet, xnt, cntA, offs, csr, n0b + r, N, r, q, feat, x0, x1);
  __syncthreads();
  short8 bfr[6];
#pragma unroll
  for (int k = 0; k < 6; ++k) bfr[k] = *(const short8*)(K1 + oc * 192 + k * 32 + g * 8);
  f32x4 acc[4] = {};
  mfma192(feat, bfr, lane, g, acc);
  float ssum = 0.f, ssq = 0.f;
#pragma unroll
  for (int it = 0; it < 4; ++it)
#pragma unroll
    for (int rg = 0; rg < 4; ++rg) {
      int row = it * 16 + 4 * g + rg;
      float v = acc[it][rg];
      if (n0b + row < N) { ssum += v; ssq += v * v; }
    }
  stats_reduce(ssum, ssq, sOut);
}

// ---- fused edge layer with LDS overlay + prefetch-preserving barriers ----
template<int WOUT, int TILES>
__global__ __launch_bounds__(256) void k_edge_f(
    const unsigned short* __restrict__ xnt, const unsigned short* __restrict__ xeIn,
    unsigned short* __restrict__ xeOut,
    const int* __restrict__ iInd, const int* __restrict__ jInd,
    const unsigned short* __restrict__ K1, const unsigned short* __restrict__ K2,
    const double* __restrict__ s1, long long c1,
    const double* __restrict__ s2, long long c2,
    long long E, float* __restrict__ out1) {
  __shared__ __align__(16) unsigned short feat[64][200];
  auto zA = (unsigned short (*)[72])(&feat[0][0]);
  auto zB = (unsigned short (*)[72])(&feat[0][0] + 4608);
  int t = threadIdx.x, wave = t >> 6, lane = t & 63;
  int oc = wave * 16 + (lane & 15), g = lane >> 4, r = t >> 2, q = t & 3;
  long long e0 = (long long)blockIdx.x * (64 * TILES);
  float mu1, rs1, mu2, rs2;
  ln_params(s1, c1, mu1, rs1);
  ln_params(s2, c2, mu2, rs2);
  short8 bfr[6];
#pragma unroll
  for (int k = 0; k < 6; ++k) bfr[k] = *(const short8*)(K1 + oc * 192 + k * 32 + g * 8);
  short8 b20 = *(const short8*)(K2 + oc * 64 + g * 8);
  short8 b21 = *(const short8*)(K2 + oc * 64 + 32 + g * 8);
  long long vi[TILES], vj[TILES];
#pragma unroll
  for (int tt = 0; tt < TILES; ++tt) {
    long long e = e0 + tt * 64 + r;
    vi[tt] = (e < E) ? iInd[e] : 0;
    vj[tt] = (e < E) ? jInd[e] : 0;
  }
  short8 ci0, ci1, cj0, cj1, xo0 = {}, xo1 = {};
  {
    const unsigned short* pi = xnt + vi[0] * 64 + q * 16;
    const unsigned short* pj = xnt + vj[0] * 64 + q * 16;
    ci0 = *(const short8*)pi; ci1 = *(const short8*)(pi + 8);
    cj0 = *(const short8*)pj; cj1 = *(const short8*)(pj + 8);
    long long e = e0 + r;
    if (e < E) {
      const unsigned short* pe = xeIn + e * 64 + q * 16;
      xo0 = *(const short8*)pe; xo1 = *(const short8*)(pe + 8);
    }
  }
  for (int tt = 0; tt < TILES; ++tt) {
    long long base = e0 + tt * 64;
    long long e = base + r;
    short8 ni0 = {}, ni1 = {}, nj0 = {}, nj1 = {}, nx0 = {}, nx1 = {};
    if (tt + 1 < TILES) {
      const unsigned short* pi = xnt + vi[tt + 1] * 64 + q * 16;
      const unsigned short* pj = xnt + vj[tt + 1] * 64 + q * 16;
      ni0 = *(const short8*)pi; ni1 = *(const short8*)(pi + 8);
      nj0 = *(const short8*)pj; nj1 = *(const short8*)(pj + 8);
      long long en = base + 64 + r;
      if (en < E) {
        const unsigned short* pe = xeIn + en * 64 + q * 16;
        nx0 = *(const short8*)pe; nx1 = *(const short8*)(pe + 8);
      }
    }
    short8 i0, i1, gg0, gg1;
#pragma unroll
    for (int c = 0; c < 8; ++c) {
      float a0 = bf2f_s(ci0[c]), b0v = bf2f_s(cj0[c]);
      float a1 = bf2f_s(ci1[c]), b1v = bf2f_s(cj1[c]);
      i0[c]  = (short)f2bf(0.5f * (a0 + b0v));
      i1[c]  = (short)f2bf(0.5f * (a1 + b1v));
      gg0[c] = (short)f2bf(a0 - b0v);
      gg1[c] = (short)f2bf(a1 - b1v);
    }
    *(short8*)&feat[r][q * 16]           = i0;
    *(short8*)&feat[r][q * 16 + 8]       = i1;
    *(short8*)&feat[r][64 + q * 16]      = xo0;
    *(short8*)&feat[r][64 + q * 16 + 8]  = xo1;
    *(short8*)&feat[r][128 + q * 16]     = gg0;
    *(short8*)&feat[r][128 + q * 16 + 8] = gg1;
    bar_lds();
    f32x4 a1c[4] = {};
    mfma192(feat, bfr, lane, g, a1c);
    bar_lds();  // feat reads done before zA overlay write
#pragma unroll
    for (int it = 0; it < 4; ++it)
#pragma unroll
      for (int rg = 0; rg < 4; ++rg)
        zA[it * 16 + 4 * g + rg][oc] = f2bf(fmaxf((a1c[it][rg] - mu1) * rs1, 0.f));
    bar_lds();
    f32x4 a2c[4] = {};
    mfma64t(zA, b20, b21, lane, g, a2c);
#pragma unroll
    for (int it = 0; it < 4; ++it)
#pragma unroll
      for (int rg = 0; rg < 4; ++rg)
        zB[it * 16 + 4 * g + rg][oc] = f2bf(a2c[it][rg]);  // disjoint from zA
    bar_lds();
    // xe_new = xe_old + H*ln(z2)
    short8 o0, o1;
#pragma unroll
    for (int c = 0; c < 8; ++c) {
      float z0v = bf2f(zB[r][q * 16 + c]);
      float z1v = bf2f(zB[r][q * 16 + 8 + c]);
      o0[c] = (short)f2bf(bf2f_s(xo0[c]) + HSTEP * ((z0v - mu2) * rs2));
      o1[c] = (short)f2bf(bf2f_s(xo1[c]) + HSTEP * ((z1v - mu2) * rs2));
    }
    if constexpr (!WOUT) {
      if (e < E) {
        unsigned short* po = xeOut + e * 64 + q * 16;
        *(short8*)po = o0;
        *(short8*)(po + 8) = o1;
      }
    } else {
      *(short8*)&zA[r][q * 16] = o0;       // zA reads done (pre-barrier)
      *(short8*)&zA[r][q * 16 + 8] = o1;
      bar_lds();
      int tc = t & 63, tr = t >> 6;
      long long ee = base + tc;
#pragma unroll
      for (int p = 0; p < 16; ++p) {
        int cc = tr + p * 4;
        if (ee < E) out1[(long long)cc * E + ee] = bf2f(zA[tc][cc]);
      }
    }
    bar_lds();  // all overlay reads done before next feat build
    ci0 = ni0; ci1 = ni1; cj0 = nj0; cj1 = nj1; xo0 = nx0; xo1 = nx1;
  }
}

// ---- fused node layer with LDS overlay ----
template<int CLOSE>
__global__ __launch_bounds__(256) void k_node_f(
    const unsigned short* __restrict__ xet, unsigned short* xnt,
    const int* __restrict__ cntA, const int* __restrict__ offs, const int* __restrict__ csr,
    const unsigned short* __restrict__ K1, const unsigned short* __restrict__ K2,
    const unsigned short* __restrict__ Kc,
    const double* __restrict__ s3, long long c3,
    int N, float* __restrict__ out0) {
  __shared__ __align__(16) unsigned short feat[64][200];
  auto zA = (unsigned short (*)[72])(&feat[0][0]);
  auto zB = (unsigned short (*)[72])(&feat[0][0] + 4608);
  int t = threadIdx.x, wave = t >> 6, lane = t & 63;
  int oc = wave * 16 + (lane & 15), g = lane >> 4, r = t >> 2, q = t & 3;
  int n0b = blockIdx.x * 64;
  int n = n0b + r;
  float mu3, rs3;
  ln_params(s3, c3, mu3, rs3);
  short8 x0, x1;
  node_gather_feat(xet, xnt, cntA, offs, csr, n, N, r, q, feat, x0, x1);
  bar_lds();
  short8 bfr[6];
#pragma unroll
  for (int k = 0; k < 6; ++k) bfr[k] = *(const short8*)(K1 + oc * 192 + k * 32 + g * 8);
  f32x4 a1c[4] = {};
  mfma192(feat, bfr, lane, g, a1c);
  bar_lds();  // feat reads done before zA overlay
#pragma unroll
  for (int it = 0; it < 4; ++it)
#pragma unroll
    for (int rg = 0; rg < 4; ++rg)
      zA[it * 16 + 4 * g + rg][oc] = f2bf(fmaxf((a1c[it][rg] - mu3) * rs3, 0.f));
  bar_lds();
  short8 b20 = *(const short8*)(K2 + oc * 64 + g * 8);
  short8 b21 = *(const short8*)(K2 + oc * 64 + 32 + g * 8);
  f32x4 a2c[4] = {};
  mfma64t(zA, b20, b21, lane, g, a2c);
#pragma unroll
  for (int it = 0; it < 4; ++it)
#pragma unroll
    for (int rg = 0; rg < 4; ++rg)
      zB[it * 16 + 4 * g + rg][oc] = f2bf(a2c[it][rg]);
  bar_lds();
  short8 w0, w1;
#pragma unroll
  for (int c = 0; c < 8; ++c) {
    float d0 = bf2f(zB[r][q * 16 + c]);
    float d1 = bf2f(zB[r][q * 16 + 8 + c]);
    w0[c] = (short)f2bf(bf2f_s(x0[c]) + HSTEP * d0);
    w1[c] = (short)f2bf(bf2f_s(x1[c]) + HSTEP * d1);
  }
  if constexpr (!CLOSE) {
    if (n < N) {
      unsigned short* po = xnt + (long long)n * 64 + q * 16;
      *(short8*)po = w0;
      *(short8*)(po + 8) = w1;
    }
  } else {
    *(short8*)&zA[r][q * 16] = w0;
    *(short8*)&zA[r][q * 16 + 8] = w1;
    bar_lds();
    short8 bc0 = *(const short8*)(Kc + oc * 64 + g * 8);
    short8 bc1 = *(const short8*)(Kc + oc * 64 + 32 + g * 8);
    f32x4 a3c[4] = {};
    mfma64t(zA, bc0, bc1, lane, g, a3c);
#pragma unroll
    for (int it = 0; it < 4; ++it)
#pragma unroll
      for (int rg = 0; rg < 4; ++rg)
        zB[it * 16 + 4 * g + rg][oc] = f2bf(a3c[it][rg]);
    bar_lds();
    int tc = t & 63, tr = t >> 6;
    int nn = n0b + tc;
#pragma unroll
    for (int p = 0; p < 16; ++p) {
      int cc = tr + p * 4;
      if (nn < N) out0[(long long)cc * N + nn] = bf2f(zB[tc][cc]);
    }
  }
}

extern "C" void kernel_launch(void* const* d_in, const int* in_sizes, int n_in,
                              void* d_out, int out_size, void* d_ws, size_t ws_size,
                              hipStream_t stream) {
  (void)n_in; (void)out_size; (void)ws_size;
  const float* xn  = (const float*)d_in[0];
  const float* xe  = (const float*)d_in[1];
  const int* iInd  = (const int*)d_in[2];
  const int* jInd  = (const int*)d_in[3];
  const float* K1N = (const float*)d_in[4];
  const float* K2N = (const float*)d_in[5];
  const float* K1E = (const float*)d_in[6];
  const float* K2E = (const float*)d_in[7];
  const float* KNc = (const float*)d_in[8];
  const float* KE1 = (const float*)d_in[9];
  const float* KE2 = (const float*)d_in[10];
  const float* KN1 = (const float*)d_in[11];
  const float* KN2 = (const float*)d_in[12];
  int N = in_sizes[0] / 64;
  long long E = in_sizes[2];
  float* out = (float*)d_out;

  long long Te = (E + 63) / 64;
  long long Tn = ((long long)N + 63) / 64;
  int gSe  = (int)((Te + 15) / 16);
  int gSn0 = (int)((Tn + 3) / 4);
  int gSn  = (int)((Tn + 7) / 8);
  int gOe  = (int)((Te + 3) / 4);
  int gOn  = (int)((Tn + 3) / 4);
  int gN1  = (int)Tn;

  auto sampCnt = [](long long W, int stride) -> long long {
    long long T = (W + 63) / 64;
    long long ns = (T + stride - 1) / stride;
    long long lastTile = (ns - 1) * (long long)stride;
    long long lastItems = W - lastTile * 64;
    if (lastItems > 64) lastItems = 64;
    return ((ns - 1) * 64 + lastItems) * 64;
  };
  long long c0n = sampCnt(N, 4);
  long long c0e = sampCnt(E, 16);
  long long cSe = c0e;
  long long c3n = sampCnt(N, 8);

  size_t off = 0;
  auto carve = [&](size_t bytes) -> void* {
    void* p = (char*)d_ws + off;
    off += (bytes + 255) & ~(size_t)255;
    return p;
  };
  unsigned short* xnt = (unsigned short*)carve((size_t)N * 64 * 2);
  unsigned short* xeP = (unsigned short*)carve((size_t)E * 64 * 2);
  unsigned short* xeQ = (unsigned short*)carve((size_t)E * 64 * 2);
  unsigned short* z1s = (unsigned short*)carve((size_t)gSe * 64 * 64 * 2);
  double* stats = (double*)carve(16 * sizeof(double));
  unsigned short* kw = (unsigned short*)carve(86016 * 2);
  int n2 = 2 * N;
  int* cnt     = (int*)carve((size_t)n2 * 4);
  int* partial = (int*)carve((size_t)n2 * 4);
  int* offs    = (int*)carve((size_t)n2 * 4);
  int* cursor  = (int*)carve((size_t)n2 * 4);
  int* bsum    = (int*)carve(256 * 4);
  int* csr     = (int*)carve((size_t)2 * E * 4);

  unsigned short* kw_K1N = kw;
  unsigned short* kw_K2N = kw + 4096;
  unsigned short* kw_K1E = kw + 8192;
  unsigned short* kw_K2E = kw + 12288;
  unsigned short* kw_KNc = kw + 16384;
  unsigned short* kw_KE1 = kw + 20480;
  unsigned short* kw_KE2 = kw + 45056;
  unsigned short* kw_KN1 = kw + 53248;
  unsigned short* kw_KN2 = kw + 77824;

  hipMemsetAsync(stats, 0, 16 * sizeof(double), stream);
  hipMemsetAsync(cnt, 0, (size_t)n2 * 4, stream);
  k_cvt_all<<<336, 256, 0, stream>>>(K1N, K2N, K1E, K2E, KNc, KE1, KE2, KN1, KN2, kw);

  int gEth = (int)((E + 255) / 256);
  int nb = (n2 + 1023) / 1024;
  k_hist<<<gEth, 256, 0, stream>>>(iInd, jInd, cnt, E, N);
  k_scan1<<<nb, 256, 0, stream>>>(cnt, n2, partial, bsum);
  k_scan2<<<1, 256, 0, stream>>>(bsum, nb);
  k_scan3<<<(n2 + 255) / 256, 256, 0, stream>>>(partial, bsum, offs, cursor, n2);
  k_fill<<<gEth, 256, 0, stream>>>(iInd, jInd, cursor, csr, E, N);

  k_s_open<<<gSn0, 256, 0, stream>>>(xn, kw_K1N, N, 4, stats + 0);
  k_s_open<<<gSe, 256, 0, stream>>>(xe, kw_K1E, E, 16, stats + 2);
  k_open_f<4><<<gOn, 256, 0, stream>>>(xn, kw_K1N, kw_K2N, stats + 0, c0n, xnt, N);
  k_open_f<4><<<gOe, 256, 0, stream>>>(xe, kw_K1E, kw_K2E, stats + 2, c0e, xeP, E);

  float* out1 = out + (long long)64 * N;
  for (int L = 0; L < 2; ++L) {
    const unsigned short* xeL = (L == 0) ? xeP : xeQ;
    const unsigned short* ke1 = kw_KE1 + L * 12288;
    const unsigned short* ke2 = kw_KE2 + L * 4096;
    const unsigned short* kn1 = kw_KN1 + L * 12288;
    const unsigned short* kn2 = kw_KN2 + L * 4096;
    double* sb = stats + 4 + L * 6;
    k_s_edge1<<<gSe, 256, 0, stream>>>(xnt, xeL, iInd, jInd, ke1, z1s, E, 16, sb);
    k_s_edge2<<<gSe, 256, 0, stream>>>(z1s, ke2, sb, cSe, E, 16, sb + 2);
    if (L == 0)
      k_edge_f<0, 4><<<gOe, 256, 0, stream>>>(xnt, xeP, xeQ, iInd, jInd, ke1, ke2,
                                              sb, cSe, sb + 2, cSe, E, nullptr);
    else
      k_edge_f<1, 4><<<gOe, 256, 0, stream>>>(xnt, xeQ, nullptr, iInd, jInd, ke1, ke2,
                                              sb, cSe, sb + 2, cSe, E, out1);
    k_s_node<<<gSn, 256, 0, stream>>>(xeL, xnt, cnt, offs, csr, kn1, N, 8, sb + 4);
    if (L == 0)
      k_node_f<0><<<gN1, 256, 0, stream>>>(xeP, xnt, cnt, offs, csr, kn1, kn2, nullptr,
                                           sb + 4, c3n, N, nullptr);
    else
      k_node_f<1><<<gN1, 256, 0, stream>>>(xeQ, xnt, cnt, offs, csr, kn1, kn2, kw_KNc,
                                           sb + 4, c3n, N, out);
  }
}